// Round 12
// baseline (1106.888 us; speedup 1.0000x reference)
//
#include <hip/hip_runtime.h>
#include <hip/hip_bf16.h>

#define DD 512
#define BM 64
#define TILES 16
#define THREADS 1024

typedef __attribute__((ext_vector_type(8))) short short8;   // 8 bf16 = 4 VGPRs (MFMA A/B frag)
typedef __attribute__((ext_vector_type(4))) float f32x4;    // MFMA C/D frag

__device__ __forceinline__ unsigned short f2bf(float f) {
  union { float f; unsigned u; } v; v.f = f;
  unsigned r = v.u + 0x7FFFu + ((v.u >> 16) & 1u);  // RNE
  return (unsigned short)(r >> 16);
}

// Pack kernel (K x N fp32, row-major) into MFMA-fragment-major bf16:
//   Bpack[((nb*16 + kt)*64 + lane)*8 + j]  holds  B[k][n]
//   with n = nb*16 + (lane&15), k = kt*32 + (lane>>4)*8 + j.
__global__ void prep_bpack(const float* __restrict__ W, unsigned short* __restrict__ Bpack) {
  const int tid = blockIdx.x * blockDim.x + threadIdx.x;   // 262144 threads
  const int n = tid & 511, k = tid >> 9;
  const float w = W[(size_t)k * DD + n];                   // coalesced read
  const int nb = n >> 4, lo = n & 15;
  const int kt = k >> 5, hi = (k >> 3) & 3, j = k & 7;
  const int lane = hi * 16 + lo;
  Bpack[(((size_t)(nb * 16 + kt)) * 64 + lane) * 8 + j] = f2bf(w);
}

// Persistent tile-pipelined fused kernel.
// Grid = 256 blocks (1/CU), each processes TILES=16 row-tiles of BM=64 rows.
// Pipeline: prefetch x(i+1) -> regs during epilogue(i); raw s_barrier (no
// vmcnt drain) keeps stores+prefetch in flight across phases; residual via
// acc-init = x + bias (C/D layout, L1/L2-hot from the prefetch).
__global__ __launch_bounds__(THREADS, 4)   // 16 waves, VGPR cap 128
void fused_ln_gemm(const float* __restrict__ x, const float* __restrict__ lns,
                   const float* __restrict__ lnb, const unsigned short* __restrict__ Bpack,
                   const float* __restrict__ bias, float* __restrict__ out) {
  __shared__ unsigned short Alds[2][BM * 512];   // 2 x 64 KB, XOR-swizzled rows

  const int t = threadIdx.x;
  const int lane = t & 63, lo = lane & 15, hi = lane >> 4;
  const int w = t >> 6;                       // wave id 0..15 -> 32-col strip
  const int r = t >> 4, g = t & 15;           // LN layout: 16 threads/row
  const long base = (long)blockIdx.x * (BM * TILES);

  const int col0 = w * 32 + lo;
  const float bv0 = bias[col0];
  const float bv1 = bias[col0 + 16];

  unsigned abase[4];
  #pragma unroll
  for (int m = 0; m < 4; ++m)
    abase[m] = (unsigned)((m * 16 + lo) * 1024 + hi * 16);
  const unsigned asw = (unsigned)((lo & 7) << 4);   // (m*16+lo)&7 == lo&7
  // B frag (nb = w*2 + nt, kt): Bpack8 + ((w*2+nt)*16 + kt)*64 + lane
  const short8* bbase = (const short8*)Bpack + (size_t)(w * 2) * 1024 + lane;

  // ---- prologue: prefetch tile 0's x into registers ---------------------
  float4 v[8];
  {
    const float* xr = x + (base + r) * DD + g * 4;
    #pragma unroll
    for (int i = 0; i < 8; ++i) v[i] = *(const float4*)(xr + i * 64);
  }

  int cur = 0;
  for (int it = 0; it < TILES; ++it) {
    const long trow0 = base + (long)it * BM;

    // ---- LN + relu from prefetched v[] -> Alds[cur] ---------------------
    {
      float s = 0.f, s2 = 0.f;
      #pragma unroll
      for (int i = 0; i < 8; ++i) {
        s  += (v[i].x + v[i].y) + (v[i].z + v[i].w);
        s2 += v[i].x * v[i].x + v[i].y * v[i].y + v[i].z * v[i].z + v[i].w * v[i].w;
      }
      #pragma unroll
      for (int m = 1; m < 16; m <<= 1) {   // 16-lane group reduce
        s  += __shfl_xor(s,  m, 64);
        s2 += __shfl_xor(s2, m, 64);
      }
      const float mu   = s * (1.f / 512.f);
      const float var  = fmaxf(s2 * (1.f / 512.f) - mu * mu, 0.f);
      const float rstd = rsqrtf(var + 1e-6f);
      #pragma unroll
      for (int i = 0; i < 8; ++i) {
        const int c = g * 4 + i * 64;
        const float4 sc = *(const float4*)(lns + c);
        const float4 bi = *(const float4*)(lnb + c);
        ushort4 hu;
        hu.x = f2bf(fmaxf((v[i].x - mu) * rstd * sc.x + bi.x, 0.f));
        hu.y = f2bf(fmaxf((v[i].y - mu) * rstd * sc.y + bi.y, 0.f));
        hu.z = f2bf(fmaxf((v[i].z - mu) * rstd * sc.z + bi.z, 0.f));
        hu.w = f2bf(fmaxf((v[i].w - mu) * rstd * sc.w + bi.w, 0.f));
        const unsigned a = (unsigned)(r * 1024 + g * 8 + i * 128) ^ (unsigned)((r & 7) << 4);
        *(ushort4*)((char*)&Alds[cur][0] + a) = hu;
      }
    }

    // ---- acc = x + bias (C/D layout; lines are L1/L2-hot) ---------------
    f32x4 acc[4][2];
    {
      const float* xc = x + (trow0 + hi * 4) * DD + col0;
      #pragma unroll
      for (int m = 0; m < 4; ++m) {
        #pragma unroll
        for (int q = 0; q < 4; ++q) {
          const float* rr = xc + (m * 16 + q) * DD;
          acc[m][0][q] = rr[0]  + bv0;
          acc[m][1][q] = rr[16] + bv1;
        }
      }
    }

    // ---- barrier WITHOUT vmcnt drain (stores/prefetch stay in flight) ---
    asm volatile("s_waitcnt lgkmcnt(0)" ::: "memory");
    __builtin_amdgcn_s_barrier();

    // ---- GEMM on Alds[cur]: pinned depth-3 B ring ------------------------
    const char* Ab = (const char*)&Alds[cur][0];
    short8 rb[3][2];
#define LOADB(s_, kt)                                                         \
    { rb[s_][0] = bbase[(0 * 16 + (kt)) * 64];                                \
      rb[s_][1] = bbase[(1 * 16 + (kt)) * 64]; }

    LOADB(0, 0);
    LOADB(1, 1);
    __builtin_amdgcn_sched_barrier(0);

    #pragma unroll
    for (int kt = 0; kt < 16; ++kt) {
      const int c3 = kt % 3;
      if (kt + 2 < 16) {
        LOADB((kt + 2) % 3, kt + 2);
      }
      __builtin_amdgcn_sched_barrier(0);
      short8 a[4];
      #pragma unroll
      for (int m = 0; m < 4; ++m)
        a[m] = *(const short8*)(Ab + ((abase[m] + (unsigned)kt * 64) ^ asw));
      #pragma unroll
      for (int m = 0; m < 4; ++m) {
        acc[m][0] = __builtin_amdgcn_mfma_f32_16x16x32_bf16(a[m], rb[c3][0], acc[m][0], 0, 0, 0);
        acc[m][1] = __builtin_amdgcn_mfma_f32_16x16x32_bf16(a[m], rb[c3][1], acc[m][1], 0, 0, 0);
      }
    }
#undef LOADB

    // ---- epilogue: prefetch x(i+1) FIRST, then store out(i) --------------
    if (it + 1 < TILES) {
      const float* xr2 = x + (trow0 + BM + r) * DD + g * 4;
      #pragma unroll
      for (int i = 0; i < 8; ++i) v[i] = *(const float4*)(xr2 + i * 64);
    }
    {
      float* oc = out + (trow0 + hi * 4) * DD + col0;
      #pragma unroll
      for (int m = 0; m < 4; ++m) {
        #pragma unroll
        for (int q = 0; q < 4; ++q) {
          float* o = oc + (m * 16 + q) * DD;
          o[0]  = acc[m][0][q];
          o[16] = acc[m][1][q];
        }
      }
    }
    cur ^= 1;
  }
}

extern "C" void kernel_launch(void* const* d_in, const int* in_sizes, int n_in,
                              void* d_out, int out_size, void* d_ws, size_t ws_size,
                              hipStream_t stream) {
  const float* x    = (const float*)d_in[0];
  const float* lns  = (const float*)d_in[1];
  const float* lnb  = (const float*)d_in[2];
  const float* W    = (const float*)d_in[3];
  const float* bias = (const float*)d_in[4];
  float* out = (float*)d_out;
  unsigned short* Bpack = (unsigned short*)d_ws;   // 512KB scratch

  const int nrows = in_sizes[0] / DD;

  prep_bpack<<<DD * DD / 256, 256, 0, stream>>>(W, Bpack);
  fused_ln_gemm<<<nrows / (BM * TILES), THREADS, 0, stream>>>(x, lns, lnb, Bpack, bias, out);
}

// Round 13
// 1079.012 us; speedup vs baseline: 1.0258x; 1.0258x over previous
//
#include <hip/hip_runtime.h>
#include <hip/hip_bf16.h>

#define DD 512
#define BM 64
#define TILES 16
#define THREADS 1024

typedef __attribute__((ext_vector_type(8))) short short8;   // 8 bf16 = 4 VGPRs (MFMA A/B frag)
typedef __attribute__((ext_vector_type(4))) float f32x4;    // MFMA C/D frag

__device__ __forceinline__ unsigned short f2bf(float f) {
  union { float f; unsigned u; } v; v.f = f;
  unsigned r = v.u + 0x7FFFu + ((v.u >> 16) & 1u);  // RNE
  return (unsigned short)(r >> 16);
}
__device__ __forceinline__ float bf2f(unsigned short u) {
  union { unsigned u; float f; } v; v.u = ((unsigned)u) << 16;
  return v.f;
}

// Pack kernel (K x N fp32, row-major) into MFMA-fragment-major bf16:
//   Bpack[((nb*16 + kt)*64 + lane)*8 + j]  holds  B[k][n]
//   with n = nb*16 + (lane&15), k = kt*32 + (lane>>4)*8 + j.
__global__ void prep_bpack(const float* __restrict__ W, unsigned short* __restrict__ Bpack) {
  const int tid = blockIdx.x * blockDim.x + threadIdx.x;   // 262144 threads
  const int n = tid & 511, k = tid >> 9;
  const float w = W[(size_t)k * DD + n];                   // coalesced read
  const int nb = n >> 4, lo = n & 15;
  const int kt = k >> 5, hi = (k >> 3) & 3, j = k & 7;
  const int lane = hi * 16 + lo;
  Bpack[(((size_t)(nb * 16 + kt)) * 64 + lane) * 8 + j] = f2bf(w);
}

// Persistent tile-pipelined fused kernel (register-disciplined).
// Grid = 256 (1 block/CU), TILES=16 row-tiles of BM=64 each.
// Per tile: issue x(i+1)->v (in flight under compute) ; GEMM(i) from Alds
// with depth-2 pinned B ring ; epilogue out = acc + Xlds + bias (stores
// never drained) ; s_barrier ; LN(i+1) -> Alds/Xlds ; lgkmcnt(0)+s_barrier.
__global__ __launch_bounds__(THREADS, 4)   // 16 waves, VGPR cap 128
void fused_ln_gemm(const float* __restrict__ x, const float* __restrict__ lns,
                   const float* __restrict__ lnb, const unsigned short* __restrict__ Bpack,
                   const float* __restrict__ bias, float* __restrict__ out) {
  __shared__ unsigned short Alds[BM * 512];   // 64 KB, h bf16, XOR-swizzled rows
  __shared__ unsigned short Xlds[BM * 512];   // 64 KB, x bf16, XOR-swizzled rows

  const int t = threadIdx.x;
  const int lane = t & 63, lo = lane & 15, hi = lane >> 4;
  const int w = t >> 6;                       // wave id 0..15 -> 32-col strip
  const int r = t >> 4, g = t & 15;           // LN layout: 16 threads/row
  const long base = (long)blockIdx.x * (BM * TILES);

  const int col0 = w * 32 + lo;
  const float bv0 = bias[col0];
  const float bv1 = bias[col0 + 16];

  unsigned abase[4];
  #pragma unroll
  for (int m = 0; m < 4; ++m)
    abase[m] = (unsigned)((m * 16 + lo) * 1024 + hi * 16);
  const unsigned asw = (unsigned)((lo & 7) << 4);   // (m*16+lo)&7 == lo&7
  // B frag (nb = w*2 + nt, kt): Bpack8 + ((w*2+nt)*16 + kt)*64 + lane
  const short8* bbase = (const short8*)Bpack + (size_t)(w * 2) * 1024 + lane;

  float4 v[8];

  // LN+relu from v[] -> Alds/Xlds (bf16, XOR-swizzled)
  auto ln_store = [&]() {
    float s = 0.f, s2 = 0.f;
    #pragma unroll
    for (int i = 0; i < 8; ++i) {
      s  += (v[i].x + v[i].y) + (v[i].z + v[i].w);
      s2 += v[i].x * v[i].x + v[i].y * v[i].y + v[i].z * v[i].z + v[i].w * v[i].w;
    }
    #pragma unroll
    for (int m = 1; m < 16; m <<= 1) {
      s  += __shfl_xor(s,  m, 64);
      s2 += __shfl_xor(s2, m, 64);
    }
    const float mu   = s * (1.f / 512.f);
    const float var  = fmaxf(s2 * (1.f / 512.f) - mu * mu, 0.f);
    const float rstd = rsqrtf(var + 1e-6f);
    #pragma unroll
    for (int i = 0; i < 8; ++i) {
      const int c = g * 4 + i * 64;
      const float4 sc = *(const float4*)(lns + c);
      const float4 bi = *(const float4*)(lnb + c);
      ushort4 hu;
      hu.x = f2bf(fmaxf((v[i].x - mu) * rstd * sc.x + bi.x, 0.f));
      hu.y = f2bf(fmaxf((v[i].y - mu) * rstd * sc.y + bi.y, 0.f));
      hu.z = f2bf(fmaxf((v[i].z - mu) * rstd * sc.z + bi.z, 0.f));
      hu.w = f2bf(fmaxf((v[i].w - mu) * rstd * sc.w + bi.w, 0.f));
      ushort4 xu = { f2bf(v[i].x), f2bf(v[i].y), f2bf(v[i].z), f2bf(v[i].w) };
      const unsigned a = (unsigned)(r * 1024 + g * 8 + i * 128) ^ (unsigned)((r & 7) << 4);
      *(ushort4*)((char*)Alds + a) = hu;
      *(ushort4*)((char*)Xlds + a) = xu;
    }
  };

  // ---- prologue: tile 0 ----
  {
    const float* xr = x + (base + r) * DD + g * 4;
    #pragma unroll
    for (int i = 0; i < 8; ++i) v[i] = *(const float4*)(xr + i * 64);
  }
  ln_store();
  asm volatile("s_waitcnt lgkmcnt(0)" ::: "memory");
  __builtin_amdgcn_s_barrier();

  #pragma unroll 1
  for (int it = 0; it < TILES; ++it) {
    const long trow0 = base + (long)it * BM;

    // ---- issue x(i+1) loads (stay in flight under GEMM + epilogue) -----
    if (it + 1 < TILES) {
      const float* xr2 = x + (trow0 + BM + r) * DD + g * 4;
      #pragma unroll
      for (int i = 0; i < 8; ++i) v[i] = *(const float4*)(xr2 + i * 64);
    }

    // ---- GEMM(it): depth-2 pinned B ring, 8 MFMA per kt ---------------
    f32x4 acc[4][2] = {};
    short8 rb[2][2];
#define LOADB(s_, kt)                                                        \
    { rb[s_][0] = bbase[(0 * 16 + (kt)) * 64];                               \
      rb[s_][1] = bbase[(1 * 16 + (kt)) * 64]; }

    LOADB(0, 0);
    __builtin_amdgcn_sched_barrier(0);
    #pragma unroll
    for (int kt = 0; kt < 16; ++kt) {
      if (kt + 1 < 16) LOADB((kt + 1) & 1, kt + 1);
      __builtin_amdgcn_sched_barrier(0);
      #pragma unroll
      for (int m = 0; m < 4; ++m) {
        const short8 a = *(const short8*)((const char*)Alds + ((abase[m] + (unsigned)kt * 64) ^ asw));
        acc[m][0] = __builtin_amdgcn_mfma_f32_16x16x32_bf16(a, rb[kt & 1][0], acc[m][0], 0, 0, 0);
        acc[m][1] = __builtin_amdgcn_mfma_f32_16x16x32_bf16(a, rb[kt & 1][1], acc[m][1], 0, 0, 0);
      }
    }
#undef LOADB

    // ---- epilogue: out = acc + x(Xlds) + bias; stores not drained ------
    {
      float* oc = out + (trow0 + hi * 4) * DD + col0;
      #pragma unroll
      for (int m = 0; m < 4; ++m) {
        #pragma unroll
        for (int q = 0; q < 4; ++q) {
          const int rl = m * 16 + hi * 4 + q;
          const unsigned xb = (unsigned)(rl * 1024 + col0 * 2) ^ (unsigned)((rl & 7) << 4);
          const float xv0 = bf2f(*(const unsigned short*)((const char*)Xlds + xb));
          const float xv1 = bf2f(*(const unsigned short*)((const char*)Xlds + (xb ^ 32u)));
          float* o = oc + (m * 16 + q) * DD;
          o[0]  = acc[m][0][q] + xv0 + bv0;
          o[16] = acc[m][1][q] + xv1 + bv1;
        }
      }
    }

    __builtin_amdgcn_s_barrier();          // all waves done reading Alds/Xlds

    if (it + 1 < TILES) ln_store();        // LN(it+1) -> Alds/Xlds

    asm volatile("s_waitcnt lgkmcnt(0)" ::: "memory");
    __builtin_amdgcn_s_barrier();          // LDS(i+1) visible to all
  }
}

extern "C" void kernel_launch(void* const* d_in, const int* in_sizes, int n_in,
                              void* d_out, int out_size, void* d_ws, size_t ws_size,
                              hipStream_t stream) {
  const float* x    = (const float*)d_in[0];
  const float* lns  = (const float*)d_in[1];
  const float* lnb  = (const float*)d_in[2];
  const float* W    = (const float*)d_in[3];
  const float* bias = (const float*)d_in[4];
  float* out = (float*)d_out;
  unsigned short* Bpack = (unsigned short*)d_ws;   // 512KB scratch

  const int nrows = in_sizes[0] / DD;

  prep_bpack<<<DD * DD / 256, 256, 0, stream>>>(W, Bpack);
  fused_ln_gemm<<<nrows / (BM * TILES), THREADS, 0, stream>>>(x, lns, lnb, Bpack, bias, out);
}

// Round 14
// 295.677 us; speedup vs baseline: 3.7436x; 3.6493x over previous
//
#include <hip/hip_runtime.h>
#include <hip/hip_bf16.h>

#define DD 512
#define BM 64
#define THREADS 1024

typedef __attribute__((ext_vector_type(8))) short short8;   // 8 bf16 = 4 VGPRs (MFMA A/B frag)
typedef __attribute__((ext_vector_type(4))) float f32x4;    // MFMA C/D frag

__device__ __forceinline__ unsigned short f2bf(float f) {
  union { float f; unsigned u; } v; v.f = f;
  unsigned r = v.u + 0x7FFFu + ((v.u >> 16) & 1u);  // RNE
  return (unsigned short)(r >> 16);
}
__device__ __forceinline__ float bf2f(unsigned short u) {
  union { unsigned u; float f; } v; v.u = ((unsigned)u) << 16;
  return v.f;
}

// Pack kernel (K x N fp32, row-major) into MFMA-fragment-major bf16:
//   Bpack[((nb*16 + kt)*64 + lane)*8 + j]  holds  B[k][n]
//   with n = nb*16 + (lane&15), k = kt*32 + (lane>>4)*8 + j.
__global__ void prep_bpack(const float* __restrict__ W, unsigned short* __restrict__ Bpack) {
  const int tid = blockIdx.x * blockDim.x + threadIdx.x;   // 262144 threads
  const int n = tid & 511, k = tid >> 9;
  const float w = W[(size_t)k * DD + n];                   // coalesced read
  const int nb = n >> 4, lo = n & 15;
  const int kt = k >> 5, hi = (k >> 3) & 3, j = k & 7;
  const int lane = hi * 16 + lo;
  Bpack[(((size_t)(nb * 16 + kt)) * 64 + lane) * 8 + j] = f2bf(w);
}

// Fused: LN -> relu -> bf16 -> GEMM(Bpack) -> +x +bias.
// Block = 64 rows x 512 cols, 1024 threads = 16 waves; wave w owns a 64x32
// strip (each B column-strip read by exactly ONE wave -> 2 GB total B L2).
// R10 structure + depth-4 sched_barrier-pinned B ring (8 loads in flight).
__global__ __launch_bounds__(THREADS, 4)   // 16 waves = 1 block/CU, VGPR cap 128
void fused_ln_gemm(const float* __restrict__ x, const float* __restrict__ lns,
                   const float* __restrict__ lnb, const unsigned short* __restrict__ Bpack,
                   const float* __restrict__ bias, float* __restrict__ out) {
  __shared__ unsigned short Alds[BM * 512];   // 64 KB, h bf16, XOR-swizzled rows
  __shared__ unsigned short Xlds[BM * 512];   // 64 KB, x bf16, XOR-swizzled rows

  const int t = threadIdx.x;
  const int lane = t & 63, lo = lane & 15, hi = lane >> 4;
  const int w = t >> 6;                       // wave id 0..15 -> 32-col strip
  const long row0 = (long)blockIdx.x * BM;

  // ---------------- LN + relu phase: 16 threads per row (64 rows) -------
  {
    const int r = t >> 4, g = t & 15;
    const float* xr = x + (row0 + r) * DD + g * 4;
    float4 v[8];
    float s = 0.f, s2 = 0.f;
    #pragma unroll
    for (int i = 0; i < 8; ++i) {
      v[i] = *(const float4*)(xr + i * 64);
      s  += (v[i].x + v[i].y) + (v[i].z + v[i].w);
      s2 += v[i].x * v[i].x + v[i].y * v[i].y + v[i].z * v[i].z + v[i].w * v[i].w;
    }
    #pragma unroll
    for (int m = 1; m < 16; m <<= 1) {   // 16-lane group reduce (within wave)
      s  += __shfl_xor(s,  m, 64);
      s2 += __shfl_xor(s2, m, 64);
    }
    const float mu   = s * (1.f / 512.f);
    const float var  = fmaxf(s2 * (1.f / 512.f) - mu * mu, 0.f);
    const float rstd = rsqrtf(var + 1e-6f);
    #pragma unroll
    for (int i = 0; i < 8; ++i) {
      const int c = g * 4 + i * 64;
      const float4 sc = *(const float4*)(lns + c);
      const float4 bi = *(const float4*)(lnb + c);
      ushort4 hu;
      hu.x = f2bf(fmaxf((v[i].x - mu) * rstd * sc.x + bi.x, 0.f));
      hu.y = f2bf(fmaxf((v[i].y - mu) * rstd * sc.y + bi.y, 0.f));
      hu.z = f2bf(fmaxf((v[i].z - mu) * rstd * sc.z + bi.z, 0.f));
      hu.w = f2bf(fmaxf((v[i].w - mu) * rstd * sc.w + bi.w, 0.f));
      ushort4 xu = { f2bf(v[i].x), f2bf(v[i].y), f2bf(v[i].z), f2bf(v[i].w) };
      // byte addr (r*1024 + c*2) ^ ((r&7)<<4) — 8B-aligned stays 8B-aligned
      const unsigned a = (unsigned)(r * 1024 + g * 8 + i * 128) ^ (unsigned)((r & 7) << 4);
      *(ushort4*)((char*)Alds + a) = hu;
      *(ushort4*)((char*)Xlds + a) = xu;
    }
  }
  __syncthreads();

  // ------- GEMM phase: pinned depth-4 B ring, no barriers in K-loop -----
  unsigned abase[4];
  #pragma unroll
  for (int m = 0; m < 4; ++m)
    abase[m] = (unsigned)((m * 16 + lo) * 1024 + hi * 16);
  const unsigned asw = (unsigned)((lo & 7) << 4);   // (m*16+lo)&7 == lo&7

  // B frag (nb = w*2 + nt, kt): Bpack8 + ((w*2+nt)*16 + kt)*64 + lane
  const short8* bbase = (const short8*)Bpack + (size_t)(w * 2) * 1024 + lane;

  short8 rb[4][2];   // depth-4 prefetch ring; indices static after unroll
#define LOADB(s, kt)                                                          \
  { rb[s][0] = bbase[(0 * 16 + (kt)) * 64];                                   \
    rb[s][1] = bbase[(1 * 16 + (kt)) * 64]; }

  LOADB(0, 0);
  LOADB(1, 1);
  LOADB(2, 2);
  __builtin_amdgcn_sched_barrier(0);   // pin: 6 loads issued before any MFMA

  f32x4 acc[4][2] = {};

  #pragma unroll
  for (int kt = 0; kt < 16; ++kt) {
    const int cur = kt & 3;
    if (kt + 3 < 16) {
      LOADB((kt + 3) & 3, kt + 3);       // issue kt+3's loads FIRST
    }
    __builtin_amdgcn_sched_barrier(0);   // loads may not sink below this
    short8 a[4];
    #pragma unroll
    for (int m = 0; m < 4; ++m)
      a[m] = *(const short8*)((const char*)Alds + ((abase[m] + (unsigned)kt * 64) ^ asw));
    #pragma unroll
    for (int m = 0; m < 4; ++m) {
      acc[m][0] = __builtin_amdgcn_mfma_f32_16x16x32_bf16(a[m], rb[cur][0], acc[m][0], 0, 0, 0);
      acc[m][1] = __builtin_amdgcn_mfma_f32_16x16x32_bf16(a[m], rb[cur][1], acc[m][1], 0, 0, 0);
    }
  }
#undef LOADB

  // ---------------- epilogue: out = x + acc + bias ----------------------
  const int col0 = w * 32 + lo;
  const float bv0 = bias[col0];
  const float bv1 = bias[col0 + 16];
  #pragma unroll
  for (int m = 0; m < 4; ++m) {
    #pragma unroll
    for (int q = 0; q < 4; ++q) {
      const int rl = m * 16 + hi * 4 + q;          // C/D: row = 4*hi + reg
      const unsigned xb = (unsigned)(rl * 1024 + col0 * 2) ^ (unsigned)((rl & 7) << 4);
      const float xv0 = bf2f(*(const unsigned short*)((const char*)Xlds + xb));
      const float xv1 = bf2f(*(const unsigned short*)((const char*)Xlds + (xb ^ 32u)));  // +16 cols: bit5 flip, XOR untouched
      float* o = out + (row0 + rl) * DD + col0;
      o[0]  = acc[m][0][q] + xv0 + bv0;
      o[16] = acc[m][1][q] + xv1 + bv1;
    }
  }
}

extern "C" void kernel_launch(void* const* d_in, const int* in_sizes, int n_in,
                              void* d_out, int out_size, void* d_ws, size_t ws_size,
                              hipStream_t stream) {
  const float* x    = (const float*)d_in[0];
  const float* lns  = (const float*)d_in[1];
  const float* lnb  = (const float*)d_in[2];
  const float* W    = (const float*)d_in[3];
  const float* bias = (const float*)d_in[4];
  float* out = (float*)d_out;
  unsigned short* Bpack = (unsigned short*)d_ws;   // 512KB scratch

  const int nrows = in_sizes[0] / DD;

  prep_bpack<<<DD * DD / 256, 256, 0, stream>>>(W, Bpack);
  fused_ln_gemm<<<nrows / BM, THREADS, 0, stream>>>(x, lns, lnb, Bpack, bias, out);
}